// Round 3
// baseline (2431.311 us; speedup 1.0000x reference)
//
#include <hip/hip_runtime.h>

// ---------- bf16 helpers (bit-level, RNE) ----------
__device__ __forceinline__ float bf2f(unsigned short u) {
    union { unsigned int i; float f; } v;
    v.i = ((unsigned int)u) << 16;
    return v.f;
}
__device__ __forceinline__ unsigned short f2bf(float f) {
    union { float f; unsigned int u; } v;
    v.f = f;
    unsigned int u = v.u;
    u += 0x7FFFu + ((u >> 16) & 1u);   // round-to-nearest-even
    return (unsigned short)(u >> 16);
}

// ---------- dtype-flag-dispatched loads ----------
__device__ __forceinline__ float loadElem(const void* p, size_t i, int isb) {
    return isb ? bf2f(((const unsigned short*)p)[i]) : ((const float*)p)[i];
}
__device__ __forceinline__ float4 load4(const void* p, size_t i4, int isb) {
    if (isb) {
        ushort4 u = ((const ushort4*)p)[i4];
        return make_float4(bf2f(u.x), bf2f(u.y), bf2f(u.z), bf2f(u.w));
    }
    return ((const float4*)p)[i4];
}

// ---------- runtime dtype detection ----------
// flags[0]: 1 if edge_index is int64 (odd 32-bit words all zero), else 0 (int32)
// flags[1]: 1 if float tensors are bf16. Test: low u16 of each sampled u32 word
//   of x, read as bf16, is a plausible N(0,1) sample (|v| in (1e-5,100)).
//   True bf16 data -> ~100% plausible; f32 data (random mantissa bits) -> ~9%.
__global__ void k_detect(const int* __restrict__ ei, int newords,
                         const unsigned int* __restrict__ xw, int nxw,
                         int* __restrict__ flags) {
    __shared__ int aOr;
    __shared__ int plaus;
    if (threadIdx.x == 0) { aOr = 0; plaus = 0; }
    __syncthreads();
    int v = 0;
    for (int i = 1 + 2 * (int)threadIdx.x; i < newords; i += 512) v |= ei[i];
    int pl = 0;
    for (int i = threadIdx.x; i < nxw; i += 256) {
        unsigned short lo = (unsigned short)(xw[i] & 0xFFFFu);
        float a = fabsf(bf2f(lo));
        if (a > 1e-5f && a < 100.0f) pl++;
    }
    atomicOr(&aOr, v);
    atomicAdd(&plaus, pl);
    __syncthreads();
    if (threadIdx.x == 0) {
        flags[0] = (aOr == 0) ? 1 : 0;
        flags[1] = (2 * plaus >= nxw) ? 1 : 0;
    }
}

// ---------- zero a float range ----------
__global__ void k_zero(float* __restrict__ p, int n) {
    int i = blockIdx.x * blockDim.x + threadIdx.x;
    if (i < n) p[i] = 0.0f;
}

// ---------- scatter: agg[dst-n0] += feat[src] for dst in [n0,n1) ----------
// 16 threads per edge, 4 channels per thread. featMode: -1 = use flags[1], 1 = bf16.
__global__ void k_scatter(const void* __restrict__ feat,
                          const int* __restrict__ ei,
                          const int* __restrict__ flags,
                          float* __restrict__ agg,
                          float* __restrict__ cnt,
                          int E, int n0, int n1, int docnt, int featMode) {
    int t = blockIdx.x * blockDim.x + threadIdx.x;
    int e = t >> 4;
    if (e >= E) return;
    int q = flags[0];
    int dst = ei[((size_t)(E + e)) << q];
    if (dst < n0 || dst >= n1) return;
    int src = ei[((size_t)e) << q];
    int cg = (t & 15) << 2;
    int fb = (featMode >= 0) ? featMode : flags[1];
    float4 v = load4(feat, (size_t)src * 16 + (cg >> 2), fb);
    float* ap = agg + ((size_t)(dst - n0)) * 64 + cg;
    atomicAdd(ap + 0, v.x);
    atomicAdd(ap + 1, v.y);
    atomicAdd(ap + 2, v.z);
    atomicAdd(ap + 3, v.w);
    if (docnt && cg == 0) atomicAdd(cnt + dst, 1.0f);
}

// ---------- layer 1: h = relu( (agg/cnt) @ W_l + x @ W_r + b ), 64 -> 64, bf16 h ----------
__global__ __launch_bounds__(256) void k_layer1(
        const void* __restrict__ x,
        const float* __restrict__ agg,
        const float* __restrict__ cnt,
        const void* __restrict__ W_l,
        const void* __restrict__ W_r,
        const void* __restrict__ b,
        unsigned short* __restrict__ h, int n0, int n1,
        const int* __restrict__ flags) {
    __shared__ float wl[64 * 64];
    __shared__ float wr[64 * 64];
    __shared__ float a_sh[4][64];
    __shared__ float x_sh[4][64];

    int isb = flags[1];
    int tid = threadIdx.x;
    for (int i = tid; i < 4096; i += 256) {
        wl[i] = loadElem(W_l, i, isb);
        wr[i] = loadElem(W_r, i, isb);
    }
    int wv = tid >> 6, lane = tid & 63;
    int node = n0 + blockIdx.x * 4 + wv;
    if (node < n1) {
        float inv = 1.0f / fmaxf(cnt[node], 1.0f);
        a_sh[wv][lane] = agg[((size_t)(node - n0)) * 64 + lane] * inv;
        x_sh[wv][lane] = loadElem(x, (size_t)node * 64 + lane, isb);
    }
    __syncthreads();
    if (node >= n1) return;

    float acc = loadElem(b, lane, isb);
#pragma unroll
    for (int k = 0; k < 64; ++k) {
        acc += a_sh[wv][k] * wl[k * 64 + lane];
        acc += x_sh[wv][k] * wr[k * 64 + lane];
    }
    h[(size_t)node * 64 + lane] = f2bf(fmaxf(acc, 0.0f));
}

// ---------- layer 2: out = (agg/cnt) @ W_l + h @ W_r + b, 64 -> 32 ----------
__global__ __launch_bounds__(256) void k_layer2(
        const unsigned short* __restrict__ h,
        const float* __restrict__ agg,
        const float* __restrict__ cnt,
        const void* __restrict__ W_l,
        const void* __restrict__ W_r,
        const void* __restrict__ b,
        void* __restrict__ out, int n0, int n1,
        const int* __restrict__ flags) {
    __shared__ float wl[64 * 32];
    __shared__ float wr[64 * 32];
    __shared__ float a_sh[8][64];
    __shared__ float h_sh[8][64];

    int isb = flags[1];
    int tid = threadIdx.x;
    for (int i = tid; i < 2048; i += 256) {
        wl[i] = loadElem(W_l, i, isb);
        wr[i] = loadElem(W_r, i, isb);
    }
    int nodeBase = n0 + blockIdx.x * 8;
    for (int i = tid; i < 8 * 64; i += 256) {
        int nl = i >> 6, k = i & 63;
        int node = nodeBase + nl;
        if (node < n1) {
            float inv = 1.0f / fmaxf(cnt[node], 1.0f);
            a_sh[nl][k] = agg[((size_t)(node - n0)) * 64 + k] * inv;
            h_sh[nl][k] = bf2f(h[(size_t)node * 64 + k]);
        }
    }
    __syncthreads();
    int nl = tid >> 5, c = tid & 31;
    int node = nodeBase + nl;
    if (node >= n1) return;

    float acc = loadElem(b, c, isb);
#pragma unroll
    for (int k = 0; k < 64; ++k) {
        acc += a_sh[nl][k] * wl[k * 32 + c];
        acc += h_sh[nl][k] * wr[k * 32 + c];
    }
    if (isb) ((unsigned short*)out)[(size_t)node * 32 + c] = f2bf(acc);
    else     ((float*)out)[(size_t)node * 32 + c] = acc;
}

extern "C" void kernel_launch(void* const* d_in, const int* in_sizes, int n_in,
                              void* d_out, int out_size, void* d_ws, size_t ws_size,
                              hipStream_t stream) {
    const void* x   = d_in[0];               // [N,64] f32 or bf16
    const int*  ei  = (const int*)d_in[1];   // [2,E] int32 or int64
    const void* W1l = d_in[2];
    const void* W1r = d_in[3];
    const void* b1  = d_in[4];
    const void* W2l = d_in[5];
    const void* W2r = d_in[6];
    const void* b2  = d_in[7];

    const int N = in_sizes[0] / 64;
    const int E = in_sizes[1] / 2;

    // ws layout: [flags 256B] [cnt: N f32] [h: N*64 bf16] [agg: chunk*64 f32]
    char* base = (char*)d_ws;
    int*   flags = (int*)base;
    float* cnt   = (float*)(base + 256);
    size_t hOff  = 256 + (((size_t)N * 4 + 255) & ~(size_t)255);
    unsigned short* hbuf = (unsigned short*)(base + hOff);
    size_t aggOff = hOff + (((size_t)N * 64 * 2 + 255) & ~(size_t)255);
    float* agg = (float*)(base + aggOff);

    int chunk = (N + 255) / 256;   // last resort
    for (int r = 1; r <= 256; r <<= 1) {
        int ch = (N + r - 1) / r;
        if (aggOff + (size_t)ch * 64 * 4 <= ws_size) { chunk = ch; break; }
    }

    const int B = 256;
    int nd = 2 * E; if (nd > 2048) nd = 2048;
    k_detect<<<1, 256, 0, stream>>>(ei, nd, (const unsigned int*)x, 512, flags);
    k_zero<<<(N + B - 1) / B, B, 0, stream>>>(cnt, N);

    const int aggElems = chunk * 64;
    const long long sth = (long long)E * 16;
    const int sblocks = (int)((sth + B - 1) / B);

    // ---- layer 1 ----
    for (int n0 = 0; n0 < N; n0 += chunk) {
        int n1 = n0 + chunk; if (n1 > N) n1 = N;
        k_zero<<<(aggElems + B - 1) / B, B, 0, stream>>>(agg, aggElems);
        k_scatter<<<sblocks, B, 0, stream>>>(x, ei, flags, agg, cnt, E, n0, n1, 1, -1);
        k_layer1<<<(n1 - n0 + 3) / 4, B, 0, stream>>>(x, agg, cnt, W1l, W1r, b1,
                                                      hbuf, n0, n1, flags);
    }

    // ---- layer 2 ----
    for (int n0 = 0; n0 < N; n0 += chunk) {
        int n1 = n0 + chunk; if (n1 > N) n1 = N;
        k_zero<<<(aggElems + B - 1) / B, B, 0, stream>>>(agg, aggElems);
        k_scatter<<<sblocks, B, 0, stream>>>(hbuf, ei, flags, agg, (float*)nullptr,
                                             E, n0, n1, 0, 1);
        k_layer2<<<(n1 - n0 + 7) / 8, B, 0, stream>>>(hbuf, agg, cnt, W2l, W2r, b2,
                                                      d_out, n0, n1, flags);
    }
}

// Round 4
// 739.178 us; speedup vs baseline: 3.2892x; 3.2892x over previous
//
#include <hip/hip_runtime.h>

// ---------- bf16 helpers (bit-level, RNE) ----------
__device__ __forceinline__ float bf2f(unsigned short u) {
    union { unsigned int i; float f; } v;
    v.i = ((unsigned int)u) << 16;
    return v.f;
}
__device__ __forceinline__ unsigned short f2bf(float f) {
    union { float f; unsigned int u; } v;
    v.f = f;
    unsigned int u = v.u;
    u += 0x7FFFu + ((u >> 16) & 1u);   // round-to-nearest-even
    return (unsigned short)(u >> 16);
}
__device__ __forceinline__ float loadElem(const void* p, size_t i, int isb) {
    return isb ? bf2f(((const unsigned short*)p)[i]) : ((const float*)p)[i];
}

#define SCAN_TILE 2048

// ---------- runtime dtype detection (proven in round 3) ----------
// flags[0]: 1 if edge_index is int64, else 0. flags[1]: 1 if floats are bf16.
__global__ void k_detect(const int* __restrict__ ei, int newords,
                         const unsigned int* __restrict__ xw, int nxw,
                         int* __restrict__ flags) {
    __shared__ int aOr;
    __shared__ int plaus;
    if (threadIdx.x == 0) { aOr = 0; plaus = 0; }
    __syncthreads();
    int v = 0;
    for (int i = 1 + 2 * (int)threadIdx.x; i < newords; i += 512) v |= ei[i];
    int pl = 0;
    for (int i = threadIdx.x; i < nxw; i += 256) {
        unsigned short lo = (unsigned short)(xw[i] & 0xFFFFu);
        float a = fabsf(bf2f(lo));
        if (a > 1e-5f && a < 100.0f) pl++;
    }
    atomicOr(&aOr, v);
    atomicAdd(&plaus, pl);
    __syncthreads();
    if (threadIdx.x == 0) {
        flags[0] = (aOr == 0) ? 1 : 0;
        flags[1] = (2 * plaus >= nxw) ? 1 : 0;
    }
}

__global__ void k_zero_int(int* __restrict__ p, int n) {
    int i = blockIdx.x * blockDim.x + threadIdx.x;
    if (i < n) p[i] = 0;
}

// ---------- CSR build: histogram of dst ----------
__global__ void k_hist(const int* __restrict__ ei, const int* __restrict__ flags,
                       int* __restrict__ deg, int E) {
    int e = blockIdx.x * blockDim.x + threadIdx.x;
    if (e >= E) return;
    int q = flags[0];
    int dst = ei[((size_t)(E + e)) << q];
    atomicAdd(&deg[dst], 1);
}

// ---------- scan phase A: per-block (SCAN_TILE elems) totals ----------
__global__ __launch_bounds__(256) void k_bsum(const int* __restrict__ deg,
                                              int* __restrict__ bsum, int N) {
    __shared__ int red[256];
    int base = blockIdx.x * SCAN_TILE;
    int t = threadIdx.x;
    int i0 = base + t * 8;
    int s = 0;
    if (i0 + 8 <= N) {
        int4 a = *(const int4*)(deg + i0);
        int4 b = *(const int4*)(deg + i0 + 4);
        s = a.x + a.y + a.z + a.w + b.x + b.y + b.z + b.w;
    } else {
        for (int j = 0; j < 8; ++j) { int i = i0 + j; if (i < N) s += deg[i]; }
    }
    red[t] = s; __syncthreads();
    for (int off = 128; off > 0; off >>= 1) {
        if (t < off) red[t] += red[t + off];
        __syncthreads();
    }
    if (t == 0) bsum[blockIdx.x] = red[0];
}

// ---------- scan phase B: single-block exclusive scan of block sums ----------
__global__ __launch_bounds__(1024) void k_bscan(const int* __restrict__ bsum,
                                                int* __restrict__ boff,
                                                int* __restrict__ rowptr,
                                                int nb, int N) {
    __shared__ int sh[1024];
    int t = threadIdx.x;
    int v = (t < nb) ? bsum[t] : 0;
    sh[t] = v; __syncthreads();
    for (int off = 1; off < 1024; off <<= 1) {
        int u = (t >= off) ? sh[t - off] : 0;
        __syncthreads();
        sh[t] += u;
        __syncthreads();
    }
    if (t < nb) boff[t] = sh[t] - v;            // exclusive
    if (t == nb - 1) rowptr[N] = sh[t];          // total edge count
}

// ---------- scan phase C: write rowptr + working offsets ----------
__global__ __launch_bounds__(256) void k_scanout(const int* __restrict__ deg,
                                                 const int* __restrict__ boff,
                                                 int* __restrict__ rowptr,
                                                 int* __restrict__ woff, int N) {
    __shared__ int red[256];
    int base = blockIdx.x * SCAN_TILE;
    int t = threadIdx.x;
    int i0 = base + t * 8;
    int v[8]; int s = 0;
    for (int j = 0; j < 8; ++j) { int i = i0 + j; v[j] = (i < N) ? deg[i] : 0; s += v[j]; }
    red[t] = s; __syncthreads();
    for (int off = 1; off < 256; off <<= 1) {
        int u = (t >= off) ? red[t - off] : 0;
        __syncthreads();
        red[t] += u;
        __syncthreads();
    }
    int off0 = boff[blockIdx.x] + (red[t] - s);  // block base + excl within block
    int run = 0;
    for (int j = 0; j < 8; ++j) {
        int i = i0 + j;
        if (i < N) { rowptr[i] = off0 + run; woff[i] = off0 + run; }
        run += v[j];
    }
}

// ---------- CSR fill: esorted grouped by dst ----------
__global__ void k_fill(const int* __restrict__ ei, const int* __restrict__ flags,
                       int* __restrict__ woff, int* __restrict__ esorted, int E) {
    int e = blockIdx.x * blockDim.x + threadIdx.x;
    if (e >= E) return;
    int q = flags[0];
    int dst = ei[((size_t)(E + e)) << q];
    int src = ei[((size_t)e) << q];
    int pos = atomicAdd(&woff[dst], 1);
    esorted[pos] = src;
}

// ---------- fused layer 1: gather-mean + relu( agg@Wl + x@Wr + b ), 64->64, bf16 h ----------
// block = 256 = 4 waves = 4 nodes; lane = channel
__global__ __launch_bounds__(256) void k_sage1(
        const void* __restrict__ x,
        const int* __restrict__ rowptr, const int* __restrict__ esorted,
        const void* __restrict__ W_l, const void* __restrict__ W_r,
        const void* __restrict__ b,
        unsigned short* __restrict__ h, int N, const int* __restrict__ flags) {
    __shared__ float wl[4096];
    __shared__ float wr[4096];
    __shared__ float a_sh[4][64];
    __shared__ float x_sh[4][64];

    int isb = flags[1];
    int tid = threadIdx.x;
    for (int i = tid; i < 4096; i += 256) {
        wl[i] = loadElem(W_l, i, isb);
        wr[i] = loadElem(W_r, i, isb);
    }
    int wv = tid >> 6, ch = tid & 63;
    int node = blockIdx.x * 4 + wv;
    if (node < N) {
        int beg = rowptr[node], end = rowptr[node + 1];
        float a = 0.0f;
        int i = beg;
        for (; i + 1 < end; i += 2) {          // 2-way ILP on the gather
            int s0 = esorted[i], s1 = esorted[i + 1];
            a += loadElem(x, (size_t)s0 * 64 + ch, isb);
            a += loadElem(x, (size_t)s1 * 64 + ch, isb);
        }
        if (i < end) a += loadElem(x, (size_t)esorted[i] * 64 + ch, isb);
        int deg = end - beg;
        a_sh[wv][ch] = a / (float)max(deg, 1);
        x_sh[wv][ch] = loadElem(x, (size_t)node * 64 + ch, isb);
    }
    __syncthreads();
    if (node >= N) return;

    float acc = loadElem(b, ch, isb);
#pragma unroll
    for (int k = 0; k < 64; ++k) {
        acc += a_sh[wv][k] * wl[k * 64 + ch];
        acc += x_sh[wv][k] * wr[k * 64 + ch];
    }
    h[(size_t)node * 64 + ch] = f2bf(fmaxf(acc, 0.0f));
}

// ---------- fused layer 2: gather-mean + agg@Wl + h@Wr + b, 64->32 ----------
// block = 256; 8 nodes per block; gather in two half-passes (wave = node)
__global__ __launch_bounds__(256) void k_sage2(
        const unsigned short* __restrict__ h,
        const int* __restrict__ rowptr, const int* __restrict__ esorted,
        const void* __restrict__ W_l, const void* __restrict__ W_r,
        const void* __restrict__ b,
        void* __restrict__ out, int N, const int* __restrict__ flags) {
    __shared__ float wl[2048];
    __shared__ float wr[2048];
    __shared__ float a_sh[8][64];
    __shared__ float h_sh[8][64];

    int isb = flags[1];
    int tid = threadIdx.x;
    for (int i = tid; i < 2048; i += 256) {
        wl[i] = loadElem(W_l, i, isb);
        wr[i] = loadElem(W_r, i, isb);
    }
    int nodeBase = blockIdx.x * 8;
#pragma unroll
    for (int half = 0; half < 2; ++half) {
        int idx = half * 256 + tid;
        int nl = idx >> 6, ch = idx & 63;
        int node = nodeBase + nl;
        if (node < N) {
            int beg = rowptr[node], end = rowptr[node + 1];
            float a = 0.0f;
            int i = beg;
            for (; i + 1 < end; i += 2) {
                int s0 = esorted[i], s1 = esorted[i + 1];
                a += bf2f(h[(size_t)s0 * 64 + ch]);
                a += bf2f(h[(size_t)s1 * 64 + ch]);
            }
            if (i < end) a += bf2f(h[(size_t)esorted[i] * 64 + ch]);
            a_sh[nl][ch] = a / (float)max(end - beg, 1);
            h_sh[nl][ch] = bf2f(h[(size_t)node * 64 + ch]);
        }
    }
    __syncthreads();
    int nl = tid >> 5, c = tid & 31;
    int node = nodeBase + nl;
    if (node >= N) return;

    float acc = loadElem(b, c, isb);
#pragma unroll
    for (int k = 0; k < 64; ++k) {
        acc += a_sh[nl][k] * wl[k * 32 + c];
        acc += h_sh[nl][k] * wr[k * 32 + c];
    }
    if (isb) ((unsigned short*)out)[(size_t)node * 32 + c] = f2bf(acc);
    else     ((float*)out)[(size_t)node * 32 + c] = acc;
}

extern "C" void kernel_launch(void* const* d_in, const int* in_sizes, int n_in,
                              void* d_out, int out_size, void* d_ws, size_t ws_size,
                              hipStream_t stream) {
    const void* x   = d_in[0];               // [N,64] bf16 (or f32; flag-detected)
    const int*  ei  = (const int*)d_in[1];   // [2,E] int32 or int64
    const void* W1l = d_in[2];
    const void* W1r = d_in[3];
    const void* b1  = d_in[4];
    const void* W2l = d_in[5];
    const void* W2r = d_in[6];
    const void* b2  = d_in[7];

    const int N = in_sizes[0] / 64;
    const int E = in_sizes[1] / 2;
    const int nb = (N + SCAN_TILE - 1) / SCAN_TILE;   // scan blocks (49 @ N=100k)

    // ws layout (256B-aligned chunks):
    // flags | deg[N] | rowptr[N+1] | woff[N] | bsum[1024] | boff[1024] | esorted[E] | h[N*64] bf16
    char* base = (char*)d_ws;
    size_t off = 0;
    auto alloc = [&](size_t bytes) { size_t o = off; off = (off + bytes + 255) & ~(size_t)255; return o; };
    int* flags   = (int*)(base + alloc(256));
    int* deg     = (int*)(base + alloc((size_t)N * 4));
    int* rowptr  = (int*)(base + alloc((size_t)(N + 1) * 4));
    int* woff    = (int*)(base + alloc((size_t)N * 4));
    int* bsum    = (int*)(base + alloc(1024 * 4));
    int* boff    = (int*)(base + alloc(1024 * 4));
    int* esorted = (int*)(base + alloc((size_t)E * 4));
    unsigned short* hbuf = (unsigned short*)(base + alloc((size_t)N * 64 * 2));
    (void)ws_size;

    const int B = 256;
    int nd = 2 * E; if (nd > 2048) nd = 2048;

    k_detect<<<1, 256, 0, stream>>>(ei, nd, (const unsigned int*)x, 512, flags);
    k_zero_int<<<(N + B - 1) / B, B, 0, stream>>>(deg, N);
    k_hist<<<(E + B - 1) / B, B, 0, stream>>>(ei, flags, deg, E);
    k_bsum<<<nb, B, 0, stream>>>(deg, bsum, N);
    k_bscan<<<1, 1024, 0, stream>>>(bsum, boff, rowptr, nb, N);
    k_scanout<<<nb, B, 0, stream>>>(deg, boff, rowptr, woff, N);
    k_fill<<<(E + B - 1) / B, B, 0, stream>>>(ei, flags, woff, esorted, E);

    k_sage1<<<(N + 3) / 4, B, 0, stream>>>(x, rowptr, esorted, W1l, W1r, b1,
                                           hbuf, N, flags);
    k_sage2<<<(N + 7) / 8, B, 0, stream>>>(hbuf, rowptr, esorted, W2l, W2r, b2,
                                           d_out, N, flags);
}

// Round 5
// 410.512 us; speedup vs baseline: 5.9226x; 1.8006x over previous
//
#include <hip/hip_runtime.h>

// ---------- bf16 helpers (bit-level, RNE) ----------
__device__ __forceinline__ float bf2f(unsigned short u) {
    union { unsigned int i; float f; } v;
    v.i = ((unsigned int)u) << 16;
    return v.f;
}
__device__ __forceinline__ unsigned short f2bf(float f) {
    union { float f; unsigned int u; } v;
    v.f = f;
    unsigned int u = v.u;
    u += 0x7FFFu + ((u >> 16) & 1u);   // round-to-nearest-even
    return (unsigned short)(u >> 16);
}
__device__ __forceinline__ float loadElem(const void* p, size_t i, int isb) {
    return isb ? bf2f(((const unsigned short*)p)[i]) : ((const float*)p)[i];
}
__device__ __forceinline__ void fma4(float4& a, float s, const float4& w) {
    a.x += s * w.x; a.y += s * w.y; a.z += s * w.z; a.w += s * w.w;
}

#define SCAN_TILE 2048

// ---------- runtime dtype detection (proven r3/r4) ----------
__global__ void k_detect(const int* __restrict__ ei, int newords,
                         const unsigned int* __restrict__ xw, int nxw,
                         int* __restrict__ flags) {
    __shared__ int aOr;
    __shared__ int plaus;
    if (threadIdx.x == 0) { aOr = 0; plaus = 0; }
    __syncthreads();
    int v = 0;
    for (int i = 1 + 2 * (int)threadIdx.x; i < newords; i += 512) v |= ei[i];
    int pl = 0;
    for (int i = threadIdx.x; i < nxw; i += 256) {
        unsigned short lo = (unsigned short)(xw[i] & 0xFFFFu);
        float a = fabsf(bf2f(lo));
        if (a > 1e-5f && a < 100.0f) pl++;
    }
    atomicOr(&aOr, v);
    atomicAdd(&plaus, pl);
    __syncthreads();
    if (threadIdx.x == 0) {
        flags[0] = (aOr == 0) ? 1 : 0;
        flags[1] = (2 * plaus >= nxw) ? 1 : 0;
    }
}

__global__ void k_zero_int(int* __restrict__ p, int n) {
    int i = blockIdx.x * blockDim.x + threadIdx.x;
    if (i < n) p[i] = 0;
}

// ---------- CSR build (proven r4) ----------
__global__ void k_hist(const int* __restrict__ ei, const int* __restrict__ flags,
                       int* __restrict__ deg, int E) {
    int e = blockIdx.x * blockDim.x + threadIdx.x;
    if (e >= E) return;
    int q = flags[0];
    int dst = ei[((size_t)(E + e)) << q];
    atomicAdd(&deg[dst], 1);
}

__global__ __launch_bounds__(256) void k_bsum(const int* __restrict__ deg,
                                              int* __restrict__ bsum, int N) {
    __shared__ int red[256];
    int base = blockIdx.x * SCAN_TILE;
    int t = threadIdx.x;
    int i0 = base + t * 8;
    int s = 0;
    if (i0 + 8 <= N) {
        int4 a = *(const int4*)(deg + i0);
        int4 b = *(const int4*)(deg + i0 + 4);
        s = a.x + a.y + a.z + a.w + b.x + b.y + b.z + b.w;
    } else {
        for (int j = 0; j < 8; ++j) { int i = i0 + j; if (i < N) s += deg[i]; }
    }
    red[t] = s; __syncthreads();
    for (int off = 128; off > 0; off >>= 1) {
        if (t < off) red[t] += red[t + off];
        __syncthreads();
    }
    if (t == 0) bsum[blockIdx.x] = red[0];
}

__global__ __launch_bounds__(1024) void k_bscan(const int* __restrict__ bsum,
                                                int* __restrict__ boff,
                                                int* __restrict__ rowptr,
                                                int nb, int N) {
    __shared__ int sh[1024];
    int t = threadIdx.x;
    int v = (t < nb) ? bsum[t] : 0;
    sh[t] = v; __syncthreads();
    for (int off = 1; off < 1024; off <<= 1) {
        int u = (t >= off) ? sh[t - off] : 0;
        __syncthreads();
        sh[t] += u;
        __syncthreads();
    }
    if (t < nb) boff[t] = sh[t] - v;
    if (t == nb - 1) rowptr[N] = sh[t];
}

__global__ __launch_bounds__(256) void k_scanout(const int* __restrict__ deg,
                                                 const int* __restrict__ boff,
                                                 int* __restrict__ rowptr,
                                                 int* __restrict__ woff, int N) {
    __shared__ int red[256];
    int base = blockIdx.x * SCAN_TILE;
    int t = threadIdx.x;
    int i0 = base + t * 8;
    int v[8]; int s = 0;
    for (int j = 0; j < 8; ++j) { int i = i0 + j; v[j] = (i < N) ? deg[i] : 0; s += v[j]; }
    red[t] = s; __syncthreads();
    for (int off = 1; off < 256; off <<= 1) {
        int u = (t >= off) ? red[t - off] : 0;
        __syncthreads();
        red[t] += u;
        __syncthreads();
    }
    int off0 = boff[blockIdx.x] + (red[t] - s);
    int run = 0;
    for (int j = 0; j < 8; ++j) {
        int i = i0 + j;
        if (i < N) { rowptr[i] = off0 + run; woff[i] = off0 + run; }
        run += v[j];
    }
}

__global__ void k_fill(const int* __restrict__ ei, const int* __restrict__ flags,
                       int* __restrict__ woff, int* __restrict__ esorted, int E) {
    int e = blockIdx.x * blockDim.x + threadIdx.x;
    if (e >= E) return;
    int q = flags[0];
    int dst = ei[((size_t)(E + e)) << q];
    int src = ei[((size_t)e) << q];
    int pos = atomicAdd(&woff[dst], 1);
    esorted[pos] = src;
}

// ---------- register-tiled dense GEMM: D = A[N,64] @ W[64,CHOUT] (+bias)(+add)(relu) ----------
// block 256; tile NPB nodes x CHOUT ch; thread owns 4 nodes x 4 ch.
// aIsB: 1 = A is bf16 (internal buffer), -1 = use flags[1].
template<int CHOUT, int NPB, bool RELU, bool HASBIAS, bool HASADD, bool FINAL>
__global__ __launch_bounds__(256) void k_gemm(
        const void* __restrict__ A, int aIsB,
        const void* __restrict__ W,
        const void* __restrict__ bias,
        const unsigned short* __restrict__ add,
        void* __restrict__ D, int N, const int* __restrict__ flags) {
    constexpr int S = NPB + 2;                 // f32 LDS row stride (8B-aligned float2 reads)
    __shared__ float As[64 * S];
    __shared__ float Ws[64 * CHOUT];
    __shared__ float Bs[CHOUT];

    int isb = flags[1];
    int ab = (aIsB >= 0) ? aIsB : isb;
    int t = threadIdx.x;

    for (int i = t; i < 64 * CHOUT; i += 256) Ws[i] = loadElem(W, i, isb);
    if (t < CHOUT) Bs[t] = HASBIAS ? loadElem(bias, t, isb) : 0.0f;

    int nodeBase = blockIdx.x * NPB;
    for (int i = t; i < NPB * 64; i += 256) {
        int node = i >> 6, k = i & 63;
        int gn = nodeBase + node;
        As[k * S + node] = (gn < N) ? loadElem(A, (size_t)gn * 64 + k, ab) : 0.0f;
    }
    __syncthreads();

    constexpr int CQ = CHOUT / 4;
    int cq = t % CQ, nq = t / CQ;
    float4 acc[4];
    acc[0] = acc[1] = acc[2] = acc[3] = make_float4(0.f, 0.f, 0.f, 0.f);

#pragma unroll 8
    for (int k = 0; k < 64; ++k) {
        const float* ar = &As[k * S + 4 * nq];
        float2 a01 = *(const float2*)ar;
        float2 a23 = *(const float2*)(ar + 2);
        float4 w = *(const float4*)&Ws[k * CHOUT + 4 * cq];
        fma4(acc[0], a01.x, w);
        fma4(acc[1], a01.y, w);
        fma4(acc[2], a23.x, w);
        fma4(acc[3], a23.y, w);
    }

    float4 bv = *(const float4*)&Bs[4 * cq];
#pragma unroll
    for (int i = 0; i < 4; ++i) {
        int node = nodeBase + 4 * nq + i;
        if (node >= N) continue;
        float4 r = acc[i];
        if (HASBIAS) { r.x += bv.x; r.y += bv.y; r.z += bv.z; r.w += bv.w; }
        if (HASADD) {
            ushort4 u = *(const ushort4*)(add + (size_t)node * CHOUT + 4 * cq);
            r.x += bf2f(u.x); r.y += bf2f(u.y); r.z += bf2f(u.z); r.w += bf2f(u.w);
        }
        if (RELU) {
            r.x = fmaxf(r.x, 0.f); r.y = fmaxf(r.y, 0.f);
            r.z = fmaxf(r.z, 0.f); r.w = fmaxf(r.w, 0.f);
        }
        if (FINAL && !isb) {
            *(float4*)((float*)D + (size_t)node * CHOUT + 4 * cq) = r;
        } else {
            ushort4 o = { f2bf(r.x), f2bf(r.y), f2bf(r.z), f2bf(r.w) };
            *(ushort4*)((unsigned short*)D + (size_t)node * CHOUT + 4 * cq) = o;
        }
    }
}

// ---------- CSR mean-gather over bf16 rows: am[node] = mean(feat[esorted[...]]) ----------
// group of GS=CH/4 lanes per node; indices register-staged, __shfl broadcast; 4 rows in flight.
template<int CH>
__global__ __launch_bounds__(256) void k_gather(
        const unsigned short* __restrict__ feat,
        const int* __restrict__ rowptr, const int* __restrict__ esorted,
        unsigned short* __restrict__ am, int N) {
    constexpr int GS = CH / 4;
    int t = threadIdx.x;
    int g = t / GS, lane = t % GS;
    int node = blockIdx.x * (256 / GS) + g;
    if (node >= N) return;
    int beg = rowptr[node], end = rowptr[node + 1];
    int gb = (t & 63) - ((t & 63) % GS);       // group base lane within wave
    float ax = 0.f, ay = 0.f, az = 0.f, aw = 0.f;

    for (int base = beg; base < end; base += GS) {
        int cnt = min(end - base, GS);
        int idx = esorted[min(base + lane, end - 1)];
        int dd = 0;
        for (; dd + 4 <= cnt; dd += 4) {
            int s0 = __shfl(idx, gb + dd + 0, 64);
            int s1 = __shfl(idx, gb + dd + 1, 64);
            int s2 = __shfl(idx, gb + dd + 2, 64);
            int s3 = __shfl(idx, gb + dd + 3, 64);
            ushort4 u0 = *(const ushort4*)(feat + (size_t)s0 * CH + 4 * lane);
            ushort4 u1 = *(const ushort4*)(feat + (size_t)s1 * CH + 4 * lane);
            ushort4 u2 = *(const ushort4*)(feat + (size_t)s2 * CH + 4 * lane);
            ushort4 u3 = *(const ushort4*)(feat + (size_t)s3 * CH + 4 * lane);
            ax += bf2f(u0.x) + bf2f(u1.x) + bf2f(u2.x) + bf2f(u3.x);
            ay += bf2f(u0.y) + bf2f(u1.y) + bf2f(u2.y) + bf2f(u3.y);
            az += bf2f(u0.z) + bf2f(u1.z) + bf2f(u2.z) + bf2f(u3.z);
            aw += bf2f(u0.w) + bf2f(u1.w) + bf2f(u2.w) + bf2f(u3.w);
        }
        for (; dd < cnt; ++dd) {
            int s = __shfl(idx, gb + dd, 64);
            ushort4 u = *(const ushort4*)(feat + (size_t)s * CH + 4 * lane);
            ax += bf2f(u.x); ay += bf2f(u.y); az += bf2f(u.z); aw += bf2f(u.w);
        }
    }
    float inv = 1.0f / (float)max(end - beg, 1);
    ushort4 o = { f2bf(ax * inv), f2bf(ay * inv), f2bf(az * inv), f2bf(aw * inv) };
    *(ushort4*)(am + (size_t)node * CH + 4 * lane) = o;
}

// ---------- fallback fused kernels (proven r4) ----------
__global__ __launch_bounds__(256) void k_sage1(
        const void* __restrict__ x,
        const int* __restrict__ rowptr, const int* __restrict__ esorted,
        const void* __restrict__ W_l, const void* __restrict__ W_r,
        const void* __restrict__ b,
        unsigned short* __restrict__ h, int N, const int* __restrict__ flags) {
    __shared__ float wl[4096];
    __shared__ float wr[4096];
    __shared__ float a_sh[4][64];
    __shared__ float x_sh[4][64];
    int isb = flags[1];
    int tid = threadIdx.x;
    for (int i = tid; i < 4096; i += 256) {
        wl[i] = loadElem(W_l, i, isb);
        wr[i] = loadElem(W_r, i, isb);
    }
    int wv = tid >> 6, ch = tid & 63;
    int node = blockIdx.x * 4 + wv;
    if (node < N) {
        int beg = rowptr[node], end = rowptr[node + 1];
        float a = 0.0f;
        int i = beg;
        for (; i + 1 < end; i += 2) {
            int s0 = esorted[i], s1 = esorted[i + 1];
            a += loadElem(x, (size_t)s0 * 64 + ch, isb);
            a += loadElem(x, (size_t)s1 * 64 + ch, isb);
        }
        if (i < end) a += loadElem(x, (size_t)esorted[i] * 64 + ch, isb);
        a_sh[wv][ch] = a / (float)max(end - beg, 1);
        x_sh[wv][ch] = loadElem(x, (size_t)node * 64 + ch, isb);
    }
    __syncthreads();
    if (node >= N) return;
    float acc = loadElem(b, ch, isb);
#pragma unroll
    for (int k = 0; k < 64; ++k) {
        acc += a_sh[wv][k] * wl[k * 64 + ch];
        acc += x_sh[wv][k] * wr[k * 64 + ch];
    }
    h[(size_t)node * 64 + ch] = f2bf(fmaxf(acc, 0.0f));
}

__global__ __launch_bounds__(256) void k_sage2(
        const unsigned short* __restrict__ h,
        const int* __restrict__ rowptr, const int* __restrict__ esorted,
        const void* __restrict__ W_l, const void* __restrict__ W_r,
        const void* __restrict__ b,
        void* __restrict__ out, int N, const int* __restrict__ flags) {
    __shared__ float wl[2048];
    __shared__ float wr[2048];
    __shared__ float a_sh[8][64];
    __shared__ float h_sh[8][64];
    int isb = flags[1];
    int tid = threadIdx.x;
    for (int i = tid; i < 2048; i += 256) {
        wl[i] = loadElem(W_l, i, isb);
        wr[i] = loadElem(W_r, i, isb);
    }
    int nodeBase = blockIdx.x * 8;
#pragma unroll
    for (int half = 0; half < 2; ++half) {
        int idx = half * 256 + tid;
        int nl = idx >> 6, ch = idx & 63;
        int node = nodeBase + nl;
        if (node < N) {
            int beg = rowptr[node], end = rowptr[node + 1];
            float a = 0.0f;
            int i = beg;
            for (; i + 1 < end; i += 2) {
                int s0 = esorted[i], s1 = esorted[i + 1];
                a += bf2f(h[(size_t)s0 * 64 + ch]);
                a += bf2f(h[(size_t)s1 * 64 + ch]);
            }
            if (i < end) a += bf2f(h[(size_t)esorted[i] * 64 + ch]);
            a_sh[nl][ch] = a / (float)max(end - beg, 1);
            h_sh[nl][ch] = bf2f(h[(size_t)node * 64 + ch]);
        }
    }
    __syncthreads();
    int nl = tid >> 5, c = tid & 31;
    int node = nodeBase + nl;
    if (node >= N) return;
    float acc = loadElem(b, c, isb);
#pragma unroll
    for (int k = 0; k < 64; ++k) {
        acc += a_sh[nl][k] * wl[k * 32 + c];
        acc += h_sh[nl][k] * wr[k * 32 + c];
    }
    if (isb) ((unsigned short*)out)[(size_t)node * 32 + c] = f2bf(acc);
    else     ((float*)out)[(size_t)node * 32 + c] = acc;
}

extern "C" void kernel_launch(void* const* d_in, const int* in_sizes, int n_in,
                              void* d_out, int out_size, void* d_ws, size_t ws_size,
                              hipStream_t stream) {
    const void* x   = d_in[0];
    const int*  ei  = (const int*)d_in[1];
    const void* W1l = d_in[2];
    const void* W1r = d_in[3];
    const void* b1  = d_in[4];
    const void* W2l = d_in[5];
    const void* W2r = d_in[6];
    const void* b2  = d_in[7];

    const int N = in_sizes[0] / 64;
    const int E = in_sizes[1] / 2;
    const int nb = (N + SCAN_TILE - 1) / SCAN_TILE;

    // ws: flags | deg | rowptr | woff | bsum | boff | esorted | bufA(N*64 bf16) | bufB(N*64 bf16)
    char* base = (char*)d_ws;
    size_t off = 0;
    auto alloc = [&](size_t bytes) { size_t o = off; off = (off + bytes + 255) & ~(size_t)255; return o; };
    int* flags   = (int*)(base + alloc(256));
    int* deg     = (int*)(base + alloc((size_t)N * 4));
    int* rowptr  = (int*)(base + alloc((size_t)(N + 1) * 4));
    int* woff    = (int*)(base + alloc((size_t)N * 4));
    int* bsum    = (int*)(base + alloc(1024 * 4));
    int* boff    = (int*)(base + alloc(1024 * 4));
    int* esorted = (int*)(base + alloc((size_t)E * 4));
    unsigned short* bufA = (unsigned short*)(base + alloc((size_t)N * 64 * 2));
    size_t needFallback = off;
    unsigned short* bufB = (unsigned short*)(base + alloc((size_t)N * 64 * 2));
    size_t needPrimary = off;

    const int B = 256;
    int nd = 2 * E; if (nd > 2048) nd = 2048;

    k_detect<<<1, 256, 0, stream>>>(ei, nd, (const unsigned int*)x, 512, flags);
    k_zero_int<<<(N + B - 1) / B, B, 0, stream>>>(deg, N);
    k_hist<<<(E + B - 1) / B, B, 0, stream>>>(ei, flags, deg, E);
    k_bsum<<<nb, B, 0, stream>>>(deg, bsum, N);
    k_bscan<<<1, 1024, 0, stream>>>(bsum, boff, rowptr, nb, N);
    k_scanout<<<nb, B, 0, stream>>>(deg, boff, rowptr, woff, N);
    k_fill<<<(E + B - 1) / B, B, 0, stream>>>(ei, flags, woff, esorted, E);

    if (ws_size >= needPrimary) {
        // ---- GEMM-first pipeline ----
        unsigned short* y1  = bufA;
        unsigned short* am  = bufB;
        unsigned short* h   = bufA;                       // overwrites y1 (dead)
        unsigned short* y2  = bufB;                       // overwrites am (dead)
        unsigned short* am2 = bufB + (size_t)N * 32;

        k_gemm<64, 64, false, false, false, false><<<(N + 63) / 64, B, 0, stream>>>(
            x, -1, W1l, nullptr, nullptr, y1, N, flags);
        k_gather<64><<<(N + 15) / 16, B, 0, stream>>>(y1, rowptr, esorted, am, N);
        k_gemm<64, 64, true, true, true, false><<<(N + 63) / 64, B, 0, stream>>>(
            x, -1, W1r, b1, am, h, N, flags);
        k_gemm<32, 128, false, false, false, false><<<(N + 127) / 128, B, 0, stream>>>(
            h, 1, W2l, nullptr, nullptr, y2, N, flags);
        k_gather<32><<<(N + 31) / 32, B, 0, stream>>>(y2, rowptr, esorted, am2, N);
        k_gemm<32, 128, false, true, true, true><<<(N + 127) / 128, B, 0, stream>>>(
            h, 1, W2r, b2, am2, d_out, N, flags);
    } else if (ws_size >= needFallback) {
        // ---- r4 fused fallback ----
        k_sage1<<<(N + 3) / 4, B, 0, stream>>>(x, rowptr, esorted, W1l, W1r, b1,
                                               bufA, N, flags);
        k_sage2<<<(N + 7) / 8, B, 0, stream>>>(bufA, rowptr, esorted, W2l, W2r, b2,
                                               d_out, N, flags);
    } else {
        // last resort: fused path anyway (matches r4's proven footprint assumption)
        k_sage1<<<(N + 3) / 4, B, 0, stream>>>(x, rowptr, esorted, W1l, W1r, b1,
                                               bufA, N, flags);
        k_sage2<<<(N + 7) / 8, B, 0, stream>>>(bufA, rowptr, esorted, W2l, W2r, b2,
                                               d_out, N, flags);
    }
}

// Round 6
// 406.301 us; speedup vs baseline: 5.9840x; 1.0104x over previous
//
#include <hip/hip_runtime.h>

// ---------- bf16 helpers (bit-level, RNE) ----------
__device__ __forceinline__ float bf2f(unsigned short u) {
    union { unsigned int i; float f; } v;
    v.i = ((unsigned int)u) << 16;
    return v.f;
}
__device__ __forceinline__ unsigned short f2bf(float f) {
    union { float f; unsigned int u; } v;
    v.f = f;
    unsigned int u = v.u;
    u += 0x7FFFu + ((u >> 16) & 1u);   // round-to-nearest-even
    return (unsigned short)(u >> 16);
}
__device__ __forceinline__ float loadElem(const void* p, size_t i, int isb) {
    return isb ? bf2f(((const unsigned short*)p)[i]) : ((const float*)p)[i];
}
__device__ __forceinline__ void fma4(float4& a, float s, const float4& w) {
    a.x += s * w.x; a.y += s * w.y; a.z += s * w.z; a.w += s * w.w;
}

#define CHUNK 4096            // edges per partition block
#define BSHIFT 8              // 256 nodes per bucket

// ---------- runtime dtype detection (proven r3-r5) ----------
__global__ void k_detect(const int* __restrict__ ei, int newords,
                         const unsigned int* __restrict__ xw, int nxw,
                         int* __restrict__ flags) {
    __shared__ int aOr;
    __shared__ int plaus;
    if (threadIdx.x == 0) { aOr = 0; plaus = 0; }
    __syncthreads();
    int v = 0;
    for (int i = 1 + 2 * (int)threadIdx.x; i < newords; i += 512) v |= ei[i];
    int pl = 0;
    for (int i = threadIdx.x; i < nxw; i += 256) {
        unsigned short lo = (unsigned short)(xw[i] & 0xFFFFu);
        float a = fabsf(bf2f(lo));
        if (a > 1e-5f && a < 100.0f) pl++;
    }
    atomicOr(&aOr, v);
    atomicAdd(&plaus, pl);
    __syncthreads();
    if (threadIdx.x == 0) {
        flags[0] = (aOr == 0) ? 1 : 0;
        flags[1] = (2 * plaus >= nxw) ? 1 : 0;
    }
}

// ---------- CSR build v2: two-level counting sort, no global atomics ----------
// K1: per-block bucket histogram. blockHist layout: [bucket][block] (write scattered,
// read contiguous in K2).
__global__ __launch_bounds__(256) void k_bcount(
        const int* __restrict__ ei, const int* __restrict__ flags,
        int* __restrict__ blockHist, int E, int NBUK, int nblk) {
    __shared__ int hist[512];
    int t = threadIdx.x;
    for (int i = t; i < NBUK; i += 256) hist[i] = 0;
    __syncthreads();
    int q = flags[0];
    int e0 = blockIdx.x * CHUNK, e1 = min(E, e0 + CHUNK);
    for (int e = e0 + t; e < e1; e += 256) {
        int dst = ei[((size_t)(E + e)) << q];
        atomicAdd(&hist[dst >> BSHIFT], 1);
    }
    __syncthreads();
    for (int i = t; i < NBUK; i += 256)
        blockHist[(size_t)i * nblk + blockIdx.x] = hist[i];
}

// K2 (single block, 1024 thr): bucket totals -> exclusive scan -> bukOff;
// per-(block,bucket) write bases -> baseT [block][bucket] (contiguous for K3).
__global__ __launch_bounds__(1024) void k_bukscan(
        const int* __restrict__ blockHist, int* __restrict__ baseT,
        int* __restrict__ bukOff, int* __restrict__ rowptr,
        int nblk, int NBUK, int E, int N) {
    __shared__ int tot[1024];
    int t = threadIdx.x;
    int total = 0;
    if (t < NBUK) {
        const int* row = blockHist + (size_t)t * nblk;
        for (int blk = 0; blk < nblk; ++blk) total += row[blk];
    }
    tot[t] = total;
    __syncthreads();
    int v = tot[t];
    for (int off = 1; off < 1024; off <<= 1) {
        int u = (t >= off) ? tot[t - off] : 0;
        __syncthreads();
        tot[t] += u;
        __syncthreads();
    }
    int excl = tot[t] - v;
    if (t < NBUK) bukOff[t] = excl;
    if (t == 0) { bukOff[NBUK] = E; rowptr[N] = E; }
    if (t < NBUK) {
        const int* row = blockHist + (size_t)t * nblk;
        int run = excl;
        for (int blk = 0; blk < nblk; ++blk) {
            baseT[(size_t)blk * NBUK + t] = run;
            run += row[blk];
        }
    }
}

// K3: partition edges into bucket-grouped packed records (src<<8 | dstLocal).
__global__ __launch_bounds__(256) void k_part(
        const int* __restrict__ ei, const int* __restrict__ flags,
        const int* __restrict__ baseT, unsigned int* __restrict__ recs,
        int E, int NBUK) {
    __shared__ int cur[512];
    int t = threadIdx.x;
    const int* bp = baseT + (size_t)blockIdx.x * NBUK;
    for (int i = t; i < NBUK; i += 256) cur[i] = bp[i];
    __syncthreads();
    int q = flags[0];
    int e0 = blockIdx.x * CHUNK, e1 = min(E, e0 + CHUNK);
    for (int e = e0 + t; e < e1; e += 256) {
        int dst = ei[((size_t)(E + e)) << q];
        int src = ei[((size_t)e) << q];
        int pos = atomicAdd(&cur[dst >> BSHIFT], 1);
        recs[pos] = ((unsigned int)src << BSHIFT) | (unsigned int)(dst & ((1 << BSHIFT) - 1));
    }
}

// K4: one workgroup per bucket: local degree count + scan -> rowptr, then
// dense scatter of src ids into the bucket's contiguous esorted range.
__global__ __launch_bounds__(256) void k_csr(
        const unsigned int* __restrict__ recs, const int* __restrict__ bukOff,
        int* __restrict__ rowptr, int* __restrict__ esorted, int N) {
    __shared__ int degLoc[256];
    __shared__ int offLoc[256];
    __shared__ int wcur[256];
    int t = threadIdx.x;
    int node0 = blockIdx.x << BSHIFT;
    int r0 = bukOff[blockIdx.x], r1 = bukOff[blockIdx.x + 1];
    degLoc[t] = 0;
    __syncthreads();
    for (int i = r0 + t; i < r1; i += 256)
        atomicAdd(&degLoc[recs[i] & 255], 1);
    __syncthreads();
    int v = degLoc[t];
    offLoc[t] = v;
    __syncthreads();
    for (int off = 1; off < 256; off <<= 1) {
        int u = (t >= off) ? offLoc[t - off] : 0;
        __syncthreads();
        offLoc[t] += u;
        __syncthreads();
    }
    int excl = offLoc[t] - v;
    int node = node0 + t;
    if (node < N) rowptr[node] = r0 + excl;
    wcur[t] = r0 + excl;
    __syncthreads();
    for (int i = r0 + t; i < r1; i += 256) {
        unsigned int rec = recs[i];
        int pos = atomicAdd(&wcur[rec & 255], 1);
        esorted[pos] = (int)(rec >> BSHIFT);
    }
}

// ---------- register-tiled dense GEMM (proven r5) ----------
template<int CHOUT, int NPB, bool RELU, bool HASBIAS, bool HASADD, bool FINAL>
__global__ __launch_bounds__(256) void k_gemm(
        const void* __restrict__ A, int aIsB,
        const void* __restrict__ W,
        const void* __restrict__ bias,
        const unsigned short* __restrict__ add,
        void* __restrict__ D, int N, const int* __restrict__ flags) {
    constexpr int S = NPB + 2;
    __shared__ float As[64 * S];
    __shared__ float Ws[64 * CHOUT];
    __shared__ float Bs[CHOUT];

    int isb = flags[1];
    int ab = (aIsB >= 0) ? aIsB : isb;
    int t = threadIdx.x;

    for (int i = t; i < 64 * CHOUT; i += 256) Ws[i] = loadElem(W, i, isb);
    if (t < CHOUT) Bs[t] = HASBIAS ? loadElem(bias, t, isb) : 0.0f;

    int nodeBase = blockIdx.x * NPB;
    for (int i = t; i < NPB * 64; i += 256) {
        int node = i >> 6, k = i & 63;
        int gn = nodeBase + node;
        As[k * S + node] = (gn < N) ? loadElem(A, (size_t)gn * 64 + k, ab) : 0.0f;
    }
    __syncthreads();

    constexpr int CQ = CHOUT / 4;
    int cq = t % CQ, nq = t / CQ;
    float4 acc[4];
    acc[0] = acc[1] = acc[2] = acc[3] = make_float4(0.f, 0.f, 0.f, 0.f);

#pragma unroll 8
    for (int k = 0; k < 64; ++k) {
        const float* ar = &As[k * S + 4 * nq];
        float2 a01 = *(const float2*)ar;
        float2 a23 = *(const float2*)(ar + 2);
        float4 w = *(const float4*)&Ws[k * CHOUT + 4 * cq];
        fma4(acc[0], a01.x, w);
        fma4(acc[1], a01.y, w);
        fma4(acc[2], a23.x, w);
        fma4(acc[3], a23.y, w);
    }

    float4 bv = *(const float4*)&Bs[4 * cq];
#pragma unroll
    for (int i = 0; i < 4; ++i) {
        int node = nodeBase + 4 * nq + i;
        if (node >= N) continue;
        float4 r = acc[i];
        if (HASBIAS) { r.x += bv.x; r.y += bv.y; r.z += bv.z; r.w += bv.w; }
        if (HASADD) {
            ushort4 u = *(const ushort4*)(add + (size_t)node * CHOUT + 4 * cq);
            r.x += bf2f(u.x); r.y += bf2f(u.y); r.z += bf2f(u.z); r.w += bf2f(u.w);
        }
        if (RELU) {
            r.x = fmaxf(r.x, 0.f); r.y = fmaxf(r.y, 0.f);
            r.z = fmaxf(r.z, 0.f); r.w = fmaxf(r.w, 0.f);
        }
        if (FINAL && !isb) {
            *(float4*)((float*)D + (size_t)node * CHOUT + 4 * cq) = r;
        } else {
            ushort4 o = { f2bf(r.x), f2bf(r.y), f2bf(r.z), f2bf(r.w) };
            *(ushort4*)((unsigned short*)D + (size_t)node * CHOUT + 4 * cq) = o;
        }
    }
}

// ---------- CSR mean-gather over bf16 rows (proven r5) ----------
template<int CH>
__global__ __launch_bounds__(256) void k_gather(
        const unsigned short* __restrict__ feat,
        const int* __restrict__ rowptr, const int* __restrict__ esorted,
        unsigned short* __restrict__ am, int N) {
    constexpr int GS = CH / 4;
    int t = threadIdx.x;
    int g = t / GS, lane = t % GS;
    int node = blockIdx.x * (256 / GS) + g;
    if (node >= N) return;
    int beg = rowptr[node], end = rowptr[node + 1];
    int gb = (t & 63) - ((t & 63) % GS);
    float ax = 0.f, ay = 0.f, az = 0.f, aw = 0.f;

    for (int base = beg; base < end; base += GS) {
        int cnt = min(end - base, GS);
        int idx = esorted[min(base + lane, end - 1)];
        int dd = 0;
        for (; dd + 4 <= cnt; dd += 4) {
            int s0 = __shfl(idx, gb + dd + 0, 64);
            int s1 = __shfl(idx, gb + dd + 1, 64);
            int s2 = __shfl(idx, gb + dd + 2, 64);
            int s3 = __shfl(idx, gb + dd + 3, 64);
            ushort4 u0 = *(const ushort4*)(feat + (size_t)s0 * CH + 4 * lane);
            ushort4 u1 = *(const ushort4*)(feat + (size_t)s1 * CH + 4 * lane);
            ushort4 u2 = *(const ushort4*)(feat + (size_t)s2 * CH + 4 * lane);
            ushort4 u3 = *(const ushort4*)(feat + (size_t)s3 * CH + 4 * lane);
            ax += bf2f(u0.x) + bf2f(u1.x) + bf2f(u2.x) + bf2f(u3.x);
            ay += bf2f(u0.y) + bf2f(u1.y) + bf2f(u2.y) + bf2f(u3.y);
            az += bf2f(u0.z) + bf2f(u1.z) + bf2f(u2.z) + bf2f(u3.z);
            aw += bf2f(u0.w) + bf2f(u1.w) + bf2f(u2.w) + bf2f(u3.w);
        }
        for (; dd < cnt; ++dd) {
            int s = __shfl(idx, gb + dd, 64);
            ushort4 u = *(const ushort4*)(feat + (size_t)s * CH + 4 * lane);
            ax += bf2f(u.x); ay += bf2f(u.y); az += bf2f(u.z); aw += bf2f(u.w);
        }
    }
    float inv = 1.0f / (float)max(end - beg, 1);
    ushort4 o = { f2bf(ax * inv), f2bf(ay * inv), f2bf(az * inv), f2bf(aw * inv) };
    *(ushort4*)(am + (size_t)node * CH + 4 * lane) = o;
}

// ---------- fused fallback (proven r4) — used only if ws is too small ----------
__global__ __launch_bounds__(256) void k_sage1(
        const void* __restrict__ x,
        const int* __restrict__ rowptr, const int* __restrict__ esorted,
        const void* __restrict__ W_l, const void* __restrict__ W_r,
        const void* __restrict__ b,
        unsigned short* __restrict__ h, int N, const int* __restrict__ flags) {
    __shared__ float wl[4096];
    __shared__ float wr[4096];
    __shared__ float a_sh[4][64];
    __shared__ float x_sh[4][64];
    int isb = flags[1];
    int tid = threadIdx.x;
    for (int i = tid; i < 4096; i += 256) {
        wl[i] = loadElem(W_l, i, isb);
        wr[i] = loadElem(W_r, i, isb);
    }
    int wv = tid >> 6, ch = tid & 63;
    int node = blockIdx.x * 4 + wv;
    if (node < N) {
        int beg = rowptr[node], end = rowptr[node + 1];
        float a = 0.0f;
        int i = beg;
        for (; i + 1 < end; i += 2) {
            int s0 = esorted[i], s1 = esorted[i + 1];
            a += loadElem(x, (size_t)s0 * 64 + ch, isb);
            a += loadElem(x, (size_t)s1 * 64 + ch, isb);
        }
        if (i < end) a += loadElem(x, (size_t)esorted[i] * 64 + ch, isb);
        a_sh[wv][ch] = a / (float)max(end - beg, 1);
        x_sh[wv][ch] = loadElem(x, (size_t)node * 64 + ch, isb);
    }
    __syncthreads();
    if (node >= N) return;
    float acc = loadElem(b, ch, isb);
#pragma unroll
    for (int k = 0; k < 64; ++k) {
        acc += a_sh[wv][k] * wl[k * 64 + ch];
        acc += x_sh[wv][k] * wr[k * 64 + ch];
    }
    h[(size_t)node * 64 + ch] = f2bf(fmaxf(acc, 0.0f));
}

__global__ __launch_bounds__(256) void k_sage2(
        const unsigned short* __restrict__ h,
        const int* __restrict__ rowptr, const int* __restrict__ esorted,
        const void* __restrict__ W_l, const void* __restrict__ W_r,
        const void* __restrict__ b,
        void* __restrict__ out, int N, const int* __restrict__ flags) {
    __shared__ float wl[2048];
    __shared__ float wr[2048];
    __shared__ float a_sh[8][64];
    __shared__ float h_sh[8][64];
    int isb = flags[1];
    int tid = threadIdx.x;
    for (int i = tid; i < 2048; i += 256) {
        wl[i] = loadElem(W_l, i, isb);
        wr[i] = loadElem(W_r, i, isb);
    }
    int nodeBase = blockIdx.x * 8;
#pragma unroll
    for (int half = 0; half < 2; ++half) {
        int idx = half * 256 + tid;
        int nl = idx >> 6, ch = idx & 63;
        int node = nodeBase + nl;
        if (node < N) {
            int beg = rowptr[node], end = rowptr[node + 1];
            float a = 0.0f;
            int i = beg;
            for (; i + 1 < end; i += 2) {
                int s0 = esorted[i], s1 = esorted[i + 1];
                a += bf2f(h[(size_t)s0 * 64 + ch]);
                a += bf2f(h[(size_t)s1 * 64 + ch]);
            }
            if (i < end) a += bf2f(h[(size_t)esorted[i] * 64 + ch]);
            a_sh[nl][ch] = a / (float)max(end - beg, 1);
            h_sh[nl][ch] = bf2f(h[(size_t)node * 64 + ch]);
        }
    }
    __syncthreads();
    int nl = tid >> 5, c = tid & 31;
    int node = nodeBase + nl;
    if (node >= N) return;
    float acc = loadElem(b, c, isb);
#pragma unroll
    for (int k = 0; k < 64; ++k) {
        acc += a_sh[nl][k] * wl[k * 32 + c];
        acc += h_sh[nl][k] * wr[k * 32 + c];
    }
    if (isb) ((unsigned short*)out)[(size_t)node * 32 + c] = f2bf(acc);
    else     ((float*)out)[(size_t)node * 32 + c] = acc;
}

extern "C" void kernel_launch(void* const* d_in, const int* in_sizes, int n_in,
                              void* d_out, int out_size, void* d_ws, size_t ws_size,
                              hipStream_t stream) {
    const void* x   = d_in[0];
    const int*  ei  = (const int*)d_in[1];
    const void* W1l = d_in[2];
    const void* W1r = d_in[3];
    const void* b1  = d_in[4];
    const void* W2l = d_in[5];
    const void* W2r = d_in[6];
    const void* b2  = d_in[7];

    const int N = in_sizes[0] / 64;
    const int E = in_sizes[1] / 2;
    const int NBUK = (N + (1 << BSHIFT) - 1) >> BSHIFT;   // 391 @ N=100k (must be <= 512)
    const int nblk = (E + CHUNK - 1) / CHUNK;             // 293 @ E=1.2M

    // ws: flags | bukOff[NBUK+1] | rowptr[N+1] | recs[E] | esorted[E] | bufA | bufB
    // blockHist + baseT overlay bufA (dead before first GEMM writes y1 there).
    char* base = (char*)d_ws;
    size_t off = 0;
    auto alloc = [&](size_t bytes) { size_t o = off; off = (off + bytes + 255) & ~(size_t)255; return o; };
    int* flags   = (int*)(base + alloc(256));
    int* bukOff  = (int*)(base + alloc((size_t)(NBUK + 1) * 4));
    int* rowptr  = (int*)(base + alloc((size_t)(N + 1) * 4));
    unsigned int* recs = (unsigned int*)(base + alloc((size_t)E * 4));
    int* esorted = (int*)(base + alloc((size_t)E * 4));
    unsigned short* bufA = (unsigned short*)(base + alloc((size_t)N * 64 * 2));
    size_t needFused = off;
    unsigned short* bufB = (unsigned short*)(base + alloc((size_t)N * 64 * 2));
    size_t needPrimary = off;

    int* blockHist = (int*)bufA;                                  // [NBUK][nblk]
    int* baseT     = blockHist + (size_t)NBUK * nblk;             // [nblk][NBUK]

    const int B = 256;
    int nd = 2 * E; if (nd > 2048) nd = 2048;

    k_detect<<<1, 256, 0, stream>>>(ei, nd, (const unsigned int*)x, 512, flags);
    k_bcount<<<nblk, B, 0, stream>>>(ei, flags, blockHist, E, NBUK, nblk);
    k_bukscan<<<1, 1024, 0, stream>>>(blockHist, baseT, bukOff, rowptr, nblk, NBUK, E, N);
    k_part<<<nblk, B, 0, stream>>>(ei, flags, baseT, recs, E, NBUK);
    k_csr<<<NBUK, B, 0, stream>>>(recs, bukOff, rowptr, esorted, N);

    if (ws_size >= needPrimary) {
        // ---- GEMM-first pipeline (proven r5) ----
        unsigned short* y1  = bufA;
        unsigned short* am  = bufB;
        unsigned short* h   = bufA;
        unsigned short* y2  = bufB;
        unsigned short* am2 = bufB + (size_t)N * 32;

        k_gemm<64, 64, false, false, false, false><<<(N + 63) / 64, B, 0, stream>>>(
            x, -1, W1l, nullptr, nullptr, y1, N, flags);
        k_gather<64><<<(N + 15) / 16, B, 0, stream>>>(y1, rowptr, esorted, am, N);
        k_gemm<64, 64, true, true, true, false><<<(N + 63) / 64, B, 0, stream>>>(
            x, -1, W1r, b1, am, h, N, flags);
        k_gemm<32, 128, false, false, false, false><<<(N + 127) / 128, B, 0, stream>>>(
            h, 1, W2l, nullptr, nullptr, y2, N, flags);
        k_gather<32><<<(N + 31) / 32, B, 0, stream>>>(y2, rowptr, esorted, am2, N);
        k_gemm<32, 128, false, true, true, true><<<(N + 127) / 128, B, 0, stream>>>(
            h, 1, W2r, b2, am2, d_out, N, flags);
    } else {
        // ---- fused fallback (r4) ----
        k_sage1<<<(N + 3) / 4, B, 0, stream>>>(x, rowptr, esorted, W1l, W1r, b1,
                                               bufA, N, flags);
        k_sage2<<<(N + 7) / 8, B, 0, stream>>>(bufA, rowptr, esorted, W2l, W2r, b2,
                                               d_out, N, flags);
        (void)needFused;
    }
}

// Round 7
// 293.457 us; speedup vs baseline: 8.2851x; 1.3845x over previous
//
#include <hip/hip_runtime.h>

// ---------- bf16 helpers (bit-level, RNE) ----------
__device__ __forceinline__ float bf2f(unsigned short u) {
    union { unsigned int i; float f; } v;
    v.i = ((unsigned int)u) << 16;
    return v.f;
}
__device__ __forceinline__ unsigned short f2bf(float f) {
    union { float f; unsigned int u; } v;
    v.f = f;
    unsigned int u = v.u;
    u += 0x7FFFu + ((u >> 16) & 1u);   // round-to-nearest-even
    return (unsigned short)(u >> 16);
}
__device__ __forceinline__ float loadElem(const void* p, size_t i, int isb) {
    return isb ? bf2f(((const unsigned short*)p)[i]) : ((const float*)p)[i];
}
__device__ __forceinline__ void fma4(float4& a, float s, const float4& w) {
    a.x += s * w.x; a.y += s * w.y; a.z += s * w.z; a.w += s * w.w;
}

#define CHUNK 4096            // edges per partition block
#define BSHIFT 8              // 256 nodes per bucket

// ---------- runtime dtype detection (proven r3-r6) ----------
__global__ void k_detect(const int* __restrict__ ei, int newords,
                         const unsigned int* __restrict__ xw, int nxw,
                         int* __restrict__ flags) {
    __shared__ int aOr;
    __shared__ int plaus;
    if (threadIdx.x == 0) { aOr = 0; plaus = 0; }
    __syncthreads();
    int v = 0;
    for (int i = 1 + 2 * (int)threadIdx.x; i < newords; i += 512) v |= ei[i];
    int pl = 0;
    for (int i = threadIdx.x; i < nxw; i += 256) {
        unsigned short lo = (unsigned short)(xw[i] & 0xFFFFu);
        float a = fabsf(bf2f(lo));
        if (a > 1e-5f && a < 100.0f) pl++;
    }
    atomicOr(&aOr, v);
    atomicAdd(&plaus, pl);
    __syncthreads();
    if (threadIdx.x == 0) {
        flags[0] = (aOr == 0) ? 1 : 0;
        flags[1] = (2 * plaus >= nxw) ? 1 : 0;
    }
}

// ---------- CSR build: counting sort with parallel scans (r6 fix) ----------
// K1: per-block bucket histogram. blockHist layout: [bucket][block].
__global__ __launch_bounds__(256) void k_bcount(
        const int* __restrict__ ei, const int* __restrict__ flags,
        int* __restrict__ blockHist, int E, int NBUK, int nblk) {
    __shared__ int hist[512];
    int t = threadIdx.x;
    for (int i = t; i < NBUK; i += 256) hist[i] = 0;
    __syncthreads();
    int q = flags[0];
    int e0 = blockIdx.x * CHUNK, e1 = min(E, e0 + CHUNK);
    for (int e = e0 + t; e < e1; e += 256) {
        int dst = ei[((size_t)(E + e)) << q];
        atomicAdd(&hist[dst >> BSHIFT], 1);
    }
    __syncthreads();
    for (int i = t; i < NBUK; i += 256)
        blockHist[(size_t)i * nblk + blockIdx.x] = hist[i];
}

// K2a: one block per bucket — exclusive scan of that bucket's row IN PLACE
// (tiled 256-wide LDS scan with carry) + bucket total out. Replaces the
// single-workgroup serial k_bukscan (121 us -> ~4 us).
__global__ __launch_bounds__(256) void k_rowscan(
        int* __restrict__ blockHist, int* __restrict__ bukTot, int nblk) {
    __shared__ int sh[256];
    int t = threadIdx.x;
    int* row = blockHist + (size_t)blockIdx.x * nblk;
    int carry = 0;
    for (int base = 0; base < nblk; base += 256) {
        int i = base + t;
        int v = (i < nblk) ? row[i] : 0;
        sh[t] = v;
        __syncthreads();
        for (int off = 1; off < 256; off <<= 1) {
            int u = (t >= off) ? sh[t - off] : 0;
            __syncthreads();
            sh[t] += u;
            __syncthreads();
        }
        int incl = sh[t];
        if (i < nblk) row[i] = carry + incl - v;   // exclusive + carry
        int tileTot = sh[255];
        __syncthreads();
        carry += tileTot;
    }
    if (t == 0) bukTot[blockIdx.x] = carry;
}

// K2b: tiny single-block exclusive scan of NBUK bucket totals -> bukOff.
__global__ __launch_bounds__(512) void k_toto(
        const int* __restrict__ bukTot, int* __restrict__ bukOff,
        int* __restrict__ rowptr, int NBUK, int E, int N) {
    __shared__ int sh[512];
    int t = threadIdx.x;
    int v = (t < NBUK) ? bukTot[t] : 0;
    sh[t] = v;
    __syncthreads();
    for (int off = 1; off < 512; off <<= 1) {
        int u = (t >= off) ? sh[t - off] : 0;
        __syncthreads();
        sh[t] += u;
        __syncthreads();
    }
    if (t < NBUK) bukOff[t] = sh[t] - v;
    if (t == 0) { bukOff[NBUK] = E; rowptr[N] = E; }
}

// K3: partition edges into bucket-grouped packed records (src<<8 | dstLocal).
// Cursor seed = scanned blockHist (per-block base within bucket) + bukOff.
__global__ __launch_bounds__(256) void k_part(
        const int* __restrict__ ei, const int* __restrict__ flags,
        const int* __restrict__ blockHist, const int* __restrict__ bukOff,
        unsigned int* __restrict__ recs, int E, int NBUK, int nblk) {
    __shared__ int cur[512];
    int t = threadIdx.x;
    for (int i = t; i < NBUK; i += 256)
        cur[i] = blockHist[(size_t)i * nblk + blockIdx.x] + bukOff[i];
    __syncthreads();
    int q = flags[0];
    int e0 = blockIdx.x * CHUNK, e1 = min(E, e0 + CHUNK);
    for (int e = e0 + t; e < e1; e += 256) {
        int dst = ei[((size_t)(E + e)) << q];
        int src = ei[((size_t)e) << q];
        int pos = atomicAdd(&cur[dst >> BSHIFT], 1);
        recs[pos] = ((unsigned int)src << BSHIFT) | (unsigned int)(dst & ((1 << BSHIFT) - 1));
    }
}

// K4: one workgroup per bucket: local degree count + scan -> rowptr, then
// dense scatter of src ids into the bucket's contiguous esorted range.
__global__ __launch_bounds__(256) void k_csr(
        const unsigned int* __restrict__ recs, const int* __restrict__ bukOff,
        int* __restrict__ rowptr, int* __restrict__ esorted, int N) {
    __shared__ int degLoc[256];
    __shared__ int offLoc[256];
    __shared__ int wcur[256];
    int t = threadIdx.x;
    int node0 = blockIdx.x << BSHIFT;
    int r0 = bukOff[blockIdx.x], r1 = bukOff[blockIdx.x + 1];
    degLoc[t] = 0;
    __syncthreads();
    for (int i = r0 + t; i < r1; i += 256)
        atomicAdd(&degLoc[recs[i] & 255], 1);
    __syncthreads();
    int v = degLoc[t];
    offLoc[t] = v;
    __syncthreads();
    for (int off = 1; off < 256; off <<= 1) {
        int u = (t >= off) ? offLoc[t - off] : 0;
        __syncthreads();
        offLoc[t] += u;
        __syncthreads();
    }
    int excl = offLoc[t] - v;
    int node = node0 + t;
    if (node < N) rowptr[node] = r0 + excl;
    wcur[t] = r0 + excl;
    __syncthreads();
    for (int i = r0 + t; i < r1; i += 256) {
        unsigned int rec = recs[i];
        int pos = atomicAdd(&wcur[rec & 255], 1);
        esorted[pos] = (int)(rec >> BSHIFT);
    }
}

// ---------- register-tiled dense GEMM (proven r5) ----------
template<int CHOUT, int NPB, bool RELU, bool HASBIAS, bool HASADD, bool FINAL>
__global__ __launch_bounds__(256) void k_gemm(
        const void* __restrict__ A, int aIsB,
        const void* __restrict__ W,
        const void* __restrict__ bias,
        const unsigned short* __restrict__ add,
        void* __restrict__ D, int N, const int* __restrict__ flags) {
    constexpr int S = NPB + 2;
    __shared__ float As[64 * S];
    __shared__ float Ws[64 * CHOUT];
    __shared__ float Bs[CHOUT];

    int isb = flags[1];
    int ab = (aIsB >= 0) ? aIsB : isb;
    int t = threadIdx.x;

    for (int i = t; i < 64 * CHOUT; i += 256) Ws[i] = loadElem(W, i, isb);
    if (t < CHOUT) Bs[t] = HASBIAS ? loadElem(bias, t, isb) : 0.0f;

    int nodeBase = blockIdx.x * NPB;
    for (int i = t; i < NPB * 64; i += 256) {
        int node = i >> 6, k = i & 63;
        int gn = nodeBase + node;
        As[k * S + node] = (gn < N) ? loadElem(A, (size_t)gn * 64 + k, ab) : 0.0f;
    }
    __syncthreads();

    constexpr int CQ = CHOUT / 4;
    int cq = t % CQ, nq = t / CQ;
    float4 acc[4];
    acc[0] = acc[1] = acc[2] = acc[3] = make_float4(0.f, 0.f, 0.f, 0.f);

#pragma unroll 8
    for (int k = 0; k < 64; ++k) {
        const float* ar = &As[k * S + 4 * nq];
        float2 a01 = *(const float2*)ar;
        float2 a23 = *(const float2*)(ar + 2);
        float4 w = *(const float4*)&Ws[k * CHOUT + 4 * cq];
        fma4(acc[0], a01.x, w);
        fma4(acc[1], a01.y, w);
        fma4(acc[2], a23.x, w);
        fma4(acc[3], a23.y, w);
    }

    float4 bv = *(const float4*)&Bs[4 * cq];
#pragma unroll
    for (int i = 0; i < 4; ++i) {
        int node = nodeBase + 4 * nq + i;
        if (node >= N) continue;
        float4 r = acc[i];
        if (HASBIAS) { r.x += bv.x; r.y += bv.y; r.z += bv.z; r.w += bv.w; }
        if (HASADD) {
            ushort4 u = *(const ushort4*)(add + (size_t)node * CHOUT + 4 * cq);
            r.x += bf2f(u.x); r.y += bf2f(u.y); r.z += bf2f(u.z); r.w += bf2f(u.w);
        }
        if (RELU) {
            r.x = fmaxf(r.x, 0.f); r.y = fmaxf(r.y, 0.f);
            r.z = fmaxf(r.z, 0.f); r.w = fmaxf(r.w, 0.f);
        }
        if (FINAL && !isb) {
            *(float4*)((float*)D + (size_t)node * CHOUT + 4 * cq) = r;
        } else {
            ushort4 o = { f2bf(r.x), f2bf(r.y), f2bf(r.z), f2bf(r.w) };
            *(ushort4*)((unsigned short*)D + (size_t)node * CHOUT + 4 * cq) = o;
        }
    }
}

// ---------- CSR mean-gather over bf16 rows (proven r5) ----------
template<int CH>
__global__ __launch_bounds__(256) void k_gather(
        const unsigned short* __restrict__ feat,
        const int* __restrict__ rowptr, const int* __restrict__ esorted,
        unsigned short* __restrict__ am, int N) {
    constexpr int GS = CH / 4;
    int t = threadIdx.x;
    int g = t / GS, lane = t % GS;
    int node = blockIdx.x * (256 / GS) + g;
    if (node >= N) return;
    int beg = rowptr[node], end = rowptr[node + 1];
    int gb = (t & 63) - ((t & 63) % GS);
    float ax = 0.f, ay = 0.f, az = 0.f, aw = 0.f;

    for (int base = beg; base < end; base += GS) {
        int cnt = min(end - base, GS);
        int idx = esorted[min(base + lane, end - 1)];
        int dd = 0;
        for (; dd + 4 <= cnt; dd += 4) {
            int s0 = __shfl(idx, gb + dd + 0, 64);
            int s1 = __shfl(idx, gb + dd + 1, 64);
            int s2 = __shfl(idx, gb + dd + 2, 64);
            int s3 = __shfl(idx, gb + dd + 3, 64);
            ushort4 u0 = *(const ushort4*)(feat + (size_t)s0 * CH + 4 * lane);
            ushort4 u1 = *(const ushort4*)(feat + (size_t)s1 * CH + 4 * lane);
            ushort4 u2 = *(const ushort4*)(feat + (size_t)s2 * CH + 4 * lane);
            ushort4 u3 = *(const ushort4*)(feat + (size_t)s3 * CH + 4 * lane);
            ax += bf2f(u0.x) + bf2f(u1.x) + bf2f(u2.x) + bf2f(u3.x);
            ay += bf2f(u0.y) + bf2f(u1.y) + bf2f(u2.y) + bf2f(u3.y);
            az += bf2f(u0.z) + bf2f(u1.z) + bf2f(u2.z) + bf2f(u3.z);
            aw += bf2f(u0.w) + bf2f(u1.w) + bf2f(u2.w) + bf2f(u3.w);
        }
        for (; dd < cnt; ++dd) {
            int s = __shfl(idx, gb + dd, 64);
            ushort4 u = *(const ushort4*)(feat + (size_t)s * CH + 4 * lane);
            ax += bf2f(u.x); ay += bf2f(u.y); az += bf2f(u.z); aw += bf2f(u.w);
        }
    }
    float inv = 1.0f / (float)max(end - beg, 1);
    ushort4 o = { f2bf(ax * inv), f2bf(ay * inv), f2bf(az * inv), f2bf(aw * inv) };
    *(ushort4*)(am + (size_t)node * CH + 4 * lane) = o;
}

// ---------- fused fallback (proven r4) — used only if ws is too small ----------
__global__ __launch_bounds__(256) void k_sage1(
        const void* __restrict__ x,
        const int* __restrict__ rowptr, const int* __restrict__ esorted,
        const void* __restrict__ W_l, const void* __restrict__ W_r,
        const void* __restrict__ b,
        unsigned short* __restrict__ h, int N, const int* __restrict__ flags) {
    __shared__ float wl[4096];
    __shared__ float wr[4096];
    __shared__ float a_sh[4][64];
    __shared__ float x_sh[4][64];
    int isb = flags[1];
    int tid = threadIdx.x;
    for (int i = tid; i < 4096; i += 256) {
        wl[i] = loadElem(W_l, i, isb);
        wr[i] = loadElem(W_r, i, isb);
    }
    int wv = tid >> 6, ch = tid & 63;
    int node = blockIdx.x * 4 + wv;
    if (node < N) {
        int beg = rowptr[node], end = rowptr[node + 1];
        float a = 0.0f;
        int i = beg;
        for (; i + 1 < end; i += 2) {
            int s0 = esorted[i], s1 = esorted[i + 1];
            a += loadElem(x, (size_t)s0 * 64 + ch, isb);
            a += loadElem(x, (size_t)s1 * 64 + ch, isb);
        }
        if (i < end) a += loadElem(x, (size_t)esorted[i] * 64 + ch, isb);
        a_sh[wv][ch] = a / (float)max(end - beg, 1);
        x_sh[wv][ch] = loadElem(x, (size_t)node * 64 + ch, isb);
    }
    __syncthreads();
    if (node >= N) return;
    float acc = loadElem(b, ch, isb);
#pragma unroll
    for (int k = 0; k < 64; ++k) {
        acc += a_sh[wv][k] * wl[k * 64 + ch];
        acc += x_sh[wv][k] * wr[k * 64 + ch];
    }
    h[(size_t)node * 64 + ch] = f2bf(fmaxf(acc, 0.0f));
}

__global__ __launch_bounds__(256) void k_sage2(
        const unsigned short* __restrict__ h,
        const int* __restrict__ rowptr, const int* __restrict__ esorted,
        const void* __restrict__ W_l, const void* __restrict__ W_r,
        const void* __restrict__ b,
        void* __restrict__ out, int N, const int* __restrict__ flags) {
    __shared__ float wl[2048];
    __shared__ float wr[2048];
    __shared__ float a_sh[8][64];
    __shared__ float h_sh[8][64];
    int isb = flags[1];
    int tid = threadIdx.x;
    for (int i = tid; i < 2048; i += 256) {
        wl[i] = loadElem(W_l, i, isb);
        wr[i] = loadElem(W_r, i, isb);
    }
    int nodeBase = blockIdx.x * 8;
#pragma unroll
    for (int half = 0; half < 2; ++half) {
        int idx = half * 256 + tid;
        int nl = idx >> 6, ch = idx & 63;
        int node = nodeBase + nl;
        if (node < N) {
            int beg = rowptr[node], end = rowptr[node + 1];
            float a = 0.0f;
            int i = beg;
            for (; i + 1 < end; i += 2) {
                int s0 = esorted[i], s1 = esorted[i + 1];
                a += bf2f(h[(size_t)s0 * 64 + ch]);
                a += bf2f(h[(size_t)s1 * 64 + ch]);
            }
            if (i < end) a += bf2f(h[(size_t)esorted[i] * 64 + ch]);
            a_sh[nl][ch] = a / (float)max(end - beg, 1);
            h_sh[nl][ch] = bf2f(h[(size_t)node * 64 + ch]);
        }
    }
    __syncthreads();
    int nl = tid >> 5, c = tid & 31;
    int node = nodeBase + nl;
    if (node >= N) return;
    float acc = loadElem(b, c, isb);
#pragma unroll
    for (int k = 0; k < 64; ++k) {
        acc += a_sh[nl][k] * wl[k * 32 + c];
        acc += h_sh[nl][k] * wr[k * 32 + c];
    }
    if (isb) ((unsigned short*)out)[(size_t)node * 32 + c] = f2bf(acc);
    else     ((float*)out)[(size_t)node * 32 + c] = acc;
}

extern "C" void kernel_launch(void* const* d_in, const int* in_sizes, int n_in,
                              void* d_out, int out_size, void* d_ws, size_t ws_size,
                              hipStream_t stream) {
    const void* x   = d_in[0];
    const int*  ei  = (const int*)d_in[1];
    const void* W1l = d_in[2];
    const void* W1r = d_in[3];
    const void* b1  = d_in[4];
    const void* W2l = d_in[5];
    const void* W2r = d_in[6];
    const void* b2  = d_in[7];

    const int N = in_sizes[0] / 64;
    const int E = in_sizes[1] / 2;
    const int NBUK = (N + (1 << BSHIFT) - 1) >> BSHIFT;   // 391 @ N=100k (must be <= 512)
    const int nblk = (E + CHUNK - 1) / CHUNK;             // 293 @ E=1.2M

    // ws: flags | bukOff[NBUK+1] | bukTot[NBUK] | rowptr[N+1] | recs[E] | esorted[E] | bufA | bufB
    // blockHist overlays bufA (dead before first GEMM writes y1 there).
    char* base = (char*)d_ws;
    size_t off = 0;
    auto alloc = [&](size_t bytes) { size_t o = off; off = (off + bytes + 255) & ~(size_t)255; return o; };
    int* flags   = (int*)(base + alloc(256));
    int* bukOff  = (int*)(base + alloc((size_t)(NBUK + 1) * 4));
    int* bukTot  = (int*)(base + alloc((size_t)NBUK * 4));
    int* rowptr  = (int*)(base + alloc((size_t)(N + 1) * 4));
    unsigned int* recs = (unsigned int*)(base + alloc((size_t)E * 4));
    int* esorted = (int*)(base + alloc((size_t)E * 4));
    unsigned short* bufA = (unsigned short*)(base + alloc((size_t)N * 64 * 2));
    size_t needFused = off;
    unsigned short* bufB = (unsigned short*)(base + alloc((size_t)N * 64 * 2));
    size_t needPrimary = off;

    int* blockHist = (int*)bufA;                                  // [NBUK][nblk]

    const int B = 256;
    int nd = 2 * E; if (nd > 2048) nd = 2048;

    k_detect<<<1, 256, 0, stream>>>(ei, nd, (const unsigned int*)x, 512, flags);
    k_bcount<<<nblk, B, 0, stream>>>(ei, flags, blockHist, E, NBUK, nblk);
    k_rowscan<<<NBUK, B, 0, stream>>>(blockHist, bukTot, nblk);
    k_toto<<<1, 512, 0, stream>>>(bukTot, bukOff, rowptr, NBUK, E, N);
    k_part<<<nblk, B, 0, stream>>>(ei, flags, blockHist, bukOff, recs, E, NBUK, nblk);
    k_csr<<<NBUK, B, 0, stream>>>(recs, bukOff, rowptr, esorted, N);

    if (ws_size >= needPrimary) {
        // ---- GEMM-first pipeline (proven r5) ----
        unsigned short* y1  = bufA;
        unsigned short* am  = bufB;
        unsigned short* h   = bufA;
        unsigned short* y2  = bufB;
        unsigned short* am2 = bufB + (size_t)N * 32;

        k_gemm<64, 64, false, false, false, false><<<(N + 63) / 64, B, 0, stream>>>(
            x, -1, W1l, nullptr, nullptr, y1, N, flags);
        k_gather<64><<<(N + 15) / 16, B, 0, stream>>>(y1, rowptr, esorted, am, N);
        k_gemm<64, 64, true, true, true, false><<<(N + 63) / 64, B, 0, stream>>>(
            x, -1, W1r, b1, am, h, N, flags);
        k_gemm<32, 128, false, false, false, false><<<(N + 127) / 128, B, 0, stream>>>(
            h, 1, W2l, nullptr, nullptr, y2, N, flags);
        k_gather<32><<<(N + 31) / 32, B, 0, stream>>>(y2, rowptr, esorted, am2, N);
        k_gemm<32, 128, false, true, true, true><<<(N + 127) / 128, B, 0, stream>>>(
            h, 1, W2r, b2, am2, d_out, N, flags);
    } else {
        // ---- fused fallback (r4) ----
        k_sage1<<<(N + 3) / 4, B, 0, stream>>>(x, rowptr, esorted, W1l, W1r, b1,
                                               bufA, N, flags);
        k_sage2<<<(N + 7) / 8, B, 0, stream>>>(bufA, rowptr, esorted, W2l, W2r, b2,
                                               d_out, N, flags);
        (void)needFused;
    }
}